// Round 7
// baseline (266.786 us; speedup 1.0000x reference)
//
#include <hip/hip_runtime.h>
#include <hip/hip_bf16.h>

#define EMB 768
#define HD 1024
#define D3 128
#define CTXN 512
#define BB 8
#define SS 64

typedef __attribute__((ext_vector_type(8))) short short8v;
typedef __attribute__((ext_vector_type(4))) float f32x4;

__device__ __forceinline__ float fast_tanh(float x) {
  float e = __expf(2.f * x);
  return 1.f - 2.f * __builtin_amdgcn_rcpf(e + 1.f);
}

struct GDesc {
  const void* A;                 // row-major [M][K], fp32 or bf16
  const __hip_bfloat16* BT;      // transposed B: [N][K] bf16
  const int* arowmap;            // optional A row gather
  const float* addrow_f;         // added to row M-1 only
  const float* bias_f;           // added to all rows
  float* Cf;                     // fp32 out
  __hip_bfloat16* Cb;            // bf16 out
  float* brow_f;                 // fp32 copy of row M-1
  int M, N, K, lda, ldbt, af32, mtiles, blk0, nblks;
};
struct GBatch { GDesc d[10]; int nd; };

// gemmz: 128x128 block, 4 waves (2x2), each wave 64x64 (4x4 frags), BK=64,
// XOR-swizzled LDS, double-buffered. Row-major outputs only.
__global__ __launch_bounds__(256) void gemmz(GBatch bat) {
  int bx = blockIdx.x;
  GDesc d = bat.d[0];
  for (int i = 1; i < bat.nd; ++i)
    if (bx >= bat.d[i].blk0) d = bat.d[i];
  int local = bx - d.blk0;
  int mt = local % d.mtiles, nt = local / d.mtiles;
  int bm0 = mt * 128, bn0 = nt * 128;

  __shared__ __hip_bfloat16 As[2][128][64];  // 16B-chunk ^ (row&7)
  __shared__ __hip_bfloat16 Bs[2][128][64];
  int tid = threadIdx.x, lane = tid & 63, wid = tid >> 6;
  int l16 = lane & 15, g = lane >> 4;
  int wm = (wid >> 1) * 64, wn = (wid & 1) * 64;
  int srow = tid >> 1, sseg = tid & 1;  // staging: 128 rows x 2 segs of 32 el
  f32x4 acc[4][4] = {};

  int agr = bm0 + srow;
  int asrc = (agr < d.M) ? (d.arowmap ? d.arowmap[agr] : agr) : -1;
  const float* Af = (const float*)d.A;
  const __hip_bfloat16* Ab = (const __hip_bfloat16*)d.A;

  float fa[32];
  short8v ba[4], bb[4];
  int nk = d.K >> 6;

  auto LD = [&](int k0) {
    if (d.af32) {
      if (asrc >= 0) {
        const float* s = Af + (long)asrc * d.lda + k0 + sseg * 32;
#pragma unroll
        for (int j = 0; j < 32; ++j) fa[j] = s[j];
      } else {
#pragma unroll
        for (int j = 0; j < 32; ++j) fa[j] = 0.f;
      }
    } else {
      if (asrc >= 0) {
        const __hip_bfloat16* s = Ab + (long)asrc * d.lda + k0 + sseg * 32;
#pragma unroll
        for (int j = 0; j < 4; ++j) ba[j] = *(const short8v*)(s + j * 8);
      } else {
        short8v z = {};
#pragma unroll
        for (int j = 0; j < 4; ++j) ba[j] = z;
      }
    }
    const __hip_bfloat16* bs = d.BT + (long)(bn0 + srow) * d.ldbt + k0 + sseg * 32;
#pragma unroll
    for (int j = 0; j < 4; ++j) bb[j] = *(const short8v*)(bs + j * 8);
  };
  auto ST = [&](int buf) {
    int r7 = srow & 7, c0 = sseg * 4;
    if (d.af32) {
#pragma unroll
      for (int j = 0; j < 4; ++j) {
        __hip_bfloat16 t8[8];
#pragma unroll
        for (int u = 0; u < 8; ++u) t8[u] = __float2bfloat16(fa[j * 8 + u]);
        *(short8v*)&As[buf][srow][((c0 + j) ^ r7) * 8] = *(short8v*)t8;
      }
    } else {
#pragma unroll
      for (int j = 0; j < 4; ++j)
        *(short8v*)&As[buf][srow][((c0 + j) ^ r7) * 8] = ba[j];
    }
#pragma unroll
    for (int j = 0; j < 4; ++j)
      *(short8v*)&Bs[buf][srow][((c0 + j) ^ r7) * 8] = bb[j];
  };

  LD(0);
  ST(0);
  __syncthreads();
  for (int it = 0; it < nk; ++it) {
    int cur = it & 1;
    if (it + 1 < nk) LD((it + 1) << 6);
    int x7 = l16 & 7;
#pragma unroll
    for (int kf = 0; kf < 2; ++kf) {
      int ch = ((kf << 2) | g) ^ x7;  // row&7 == l16&7 for all fragment rows
      short8v a[4], b[4];
#pragma unroll
      for (int f = 0; f < 4; ++f)
        a[f] = *(const short8v*)&As[cur][wm + f * 16 + l16][ch * 8];
#pragma unroll
      for (int f = 0; f < 4; ++f)
        b[f] = *(const short8v*)&Bs[cur][wn + f * 16 + l16][ch * 8];
#pragma unroll
      for (int fm = 0; fm < 4; ++fm)
#pragma unroll
        for (int fn = 0; fn < 4; ++fn)
          acc[fm][fn] =
              __builtin_amdgcn_mfma_f32_16x16x32_bf16(a[fm], b[fn], acc[fm][fn], 0, 0, 0);
    }
    if (it + 1 < nk) ST(cur ^ 1);
    __syncthreads();
  }

#pragma unroll
  for (int fn = 0; fn < 4; ++fn) {
    int gcol = bn0 + wn + fn * 16 + l16;
    float bias = d.bias_f ? d.bias_f[gcol] : 0.f;
#pragma unroll
    for (int fm = 0; fm < 4; ++fm)
#pragma unroll
      for (int r = 0; r < 4; ++r) {
        int grow = bm0 + wm + fm * 16 + g * 4 + r;
        if (grow < d.M) {
          float v = acc[fm][fn][r] + bias;
          if (d.addrow_f && grow == d.M - 1) v += d.addrow_f[gcol];
          if (d.Cf) d.Cf[(long)grow * d.N + gcol] = v;
          if (d.Cb) d.Cb[(long)grow * d.N + gcol] = __float2bfloat16(v);
          if (d.brow_f && grow == d.M - 1) d.brow_f[gcol] = v;
        }
      }
  }
}

// kcast: bf16 casts + one-time transposes + g0 + qb + rowmap
__global__ __launch_bounds__(256) void kcast(const float* __restrict__ W_s,
                                             const float* __restrict__ b_s,
                                             const float* __restrict__ context,
                                             const float* __restrict__ b_in,
                                             const float* __restrict__ W_att_in,
                                             const float* __restrict__ b_att_in,
                                             const float* __restrict__ W_att_h,
                                             const float* __restrict__ W_in,
                                             const int* __restrict__ ids,
                                             __hip_bfloat16* __restrict__ Mb0,
                                             __hip_bfloat16* __restrict__ Mb0T,
                                             __hip_bfloat16* __restrict__ Z0T,
                                             __hip_bfloat16* __restrict__ WahT,
                                             __hip_bfloat16* __restrict__ WaiT,
                                             __hip_bfloat16* __restrict__ Winb,
                                             __hip_bfloat16* __restrict__ Gb,
                                             float* __restrict__ qb,
                                             int* __restrict__ rowmap) {
  int blk = blockIdx.x, tid = threadIdx.x;
  __shared__ __hip_bfloat16 tl[64][65];
  __shared__ float red[2][128];

  auto TP = [&](const float* src, int R, int C, __hip_bfloat16* dst, int tr, int tc) {
    int r0 = tr * 64, c0 = tc * 64;
    {
      int r = tid >> 2, cs = (tid & 3) * 16;
      const float* s = src + (long)(r0 + r) * C + c0 + cs;
#pragma unroll
      for (int j = 0; j < 16; ++j) tl[cs + j][r] = __float2bfloat16(s[j]);
    }
    __syncthreads();
    {
      int c = tid >> 2, rs = (tid & 3) * 16;
      __hip_bfloat16 o[16];
#pragma unroll
      for (int j = 0; j < 16; ++j) o[j] = tl[c][rs + j];
      *(short8v*)&dst[(long)(c0 + c) * R + r0 + rs] = *(short8v*)&o[0];
      *(short8v*)&dst[(long)(c0 + c) * R + r0 + rs + 8] = *(short8v*)&o[8];
    }
  };

  if (blk < 256) {
    long base = (long)blk * 4096;
    for (int i = tid; i < 4096; i += 256)
      Mb0[base + i] = __float2bfloat16(W_s[base + i]);
  } else if (blk == 256) {
    for (int i = tid; i < HD; i += 256)
      Mb0[(long)HD * HD + i] = __float2bfloat16(b_s[i]);
  } else if (blk < 513) {
    int t = blk - 257;
    TP(W_s, 1024, 1024, Mb0T, t >> 4, t & 15);
  } else if (blk < 545) {
    int t = blk - 513;
    TP(W_att_in + (long)1024 * D3, 1024, 128, Z0T, t >> 1, t & 1);
  } else if (blk < 577) {
    int t = blk - 545;
    TP(W_att_h, 1024, 128, WahT, t >> 1, t & 1);
  } else if (blk < 609) {
    int t = blk - 577;
    TP(W_att_in, 1024, 128, WaiT, t >> 1, t & 1);
  } else if (blk == 609) {
    for (int i = tid; i < BB * HD; i += 256) {
      int b = i >> 10, k = i & 1023;
      Gb[i] = __float2bfloat16(context[((long)b * CTXN + CTXN - 1) * HD + k]);
    }
  } else if (blk == 610) {
    int dd = tid & 127, h = tid >> 7;
    float acc = 0.f;
    for (int k = h * 512; k < h * 512 + 512; ++k)
      acc += b_in[k] * W_att_in[k * D3 + dd];
    red[h][dd] = acc;
    __syncthreads();
    if (h == 0) qb[dd] = red[0][dd] + red[1][dd] + b_att_in[dd];
  } else if (blk == 611) {
    for (int i = tid; i < 512; i += 256) {
      int t = i >> 3, b = i & 7;
      rowmap[i] = ids[b * SS + t];
    }
  } else {
    long base = (long)(blk - 612) * 4096;
    for (int i = tid; i < 4096; i += 256)
      Winb[base + i] = __float2bfloat16(W_in[base + i]);
  }
}

// katt: out[b][t][c] = sum_d V[d]*tanh(qF[t*8+b][d] + qH[t&7][(t>>3)*8+b][d] + ctxp[b][c][d])
__global__ __launch_bounds__(256) void katt(const float* __restrict__ qF,
                                            const float* __restrict__ qH,
                                            const float* __restrict__ ctxp,
                                            const float* __restrict__ V,
                                            float* __restrict__ out) {
  int blk = blockIdx.x;
  int b = blk >> 5, tt = (blk >> 4) & 1, ct = blk & 15;
  int t0 = tt * 32, c0 = ct * 32;
  int tid = threadIdx.x;
  __shared__ float lq[32][128];
  __shared__ float lc[32][132];
  __shared__ float lv[128];
  for (int i = tid; i < 32 * 128; i += 256) {
    int r = i >> 7, d = i & 127;
    int t = t0 + r;
    lq[r][d] = qF[((long)t * 8 + b) * 128 + d] +
               qH[(((long)(t & 7)) * 64 + (t >> 3) * 8 + b) * 128 + d];
    lc[r][d] = ctxp[((long)b * CTXN + c0 + r) * D3 + d];
  }
  if (tid < 128) lv[tid] = V[tid];
  __syncthreads();
  int cl = tid & 31, tg = tid >> 5;
  float r[4] = {0.f, 0.f, 0.f, 0.f};
  for (int d4 = 0; d4 < 32; ++d4) {
    float4 cv = *reinterpret_cast<const float4*>(&lc[cl][d4 * 4]);
    float4 vv = *reinterpret_cast<const float4*>(&lv[d4 * 4]);
#pragma unroll
    for (int u = 0; u < 4; ++u) {
      int t = tg + u * 8;
      float4 qv = *reinterpret_cast<const float4*>(&lq[t][d4 * 4]);
      r[u] = fmaf(vv.x, fast_tanh(qv.x + cv.x), r[u]);
      r[u] = fmaf(vv.y, fast_tanh(qv.y + cv.y), r[u]);
      r[u] = fmaf(vv.z, fast_tanh(qv.z + cv.z), r[u]);
      r[u] = fmaf(vv.w, fast_tanh(qv.w + cv.w), r[u]);
    }
  }
#pragma unroll
  for (int u = 0; u < 4; ++u) {
    int t = tg + u * 8;
    out[((long)b * SS + (t0 + t)) * CTXN + c0 + cl] = r[u];
  }
  if (blk == 0) {
    for (int i = tid; i < SS * BB; i += 256) out[(long)BB * SS * CTXN + i] = 0.f;
  }
}

static inline GDesc mk(const void* A, int af32, int lda, const int* arowmap,
                       const __hip_bfloat16* BT, int ldbt, int M, int N, int K,
                       const float* addrow_f, const float* bias_f, float* Cf,
                       __hip_bfloat16* Cb, float* brow_f, int blk0) {
  GDesc d;
  d.A = A; d.BT = BT; d.arowmap = arowmap;
  d.addrow_f = addrow_f; d.bias_f = bias_f;
  d.Cf = Cf; d.Cb = Cb; d.brow_f = brow_f;
  d.M = M; d.N = N; d.K = K; d.lda = lda; d.ldbt = ldbt;
  d.af32 = af32;
  d.mtiles = (M + 127) >> 7;
  d.blk0 = blk0;
  d.nblks = d.mtiles * (N >> 7);
  return d;
}

extern "C" void kernel_launch(void* const* d_in, const int* in_sizes, int n_in,
                              void* d_out, int out_size, void* d_ws, size_t ws_size,
                              hipStream_t stream) {
  const int* ids = (const int*)d_in[0];
  const float* context = (const float*)d_in[4];
  const float* emb = (const float*)d_in[5];
  const float* W_in = (const float*)d_in[6];
  const float* b_in = (const float*)d_in[7];
  const float* W_s = (const float*)d_in[8];
  const float* b_s = (const float*)d_in[9];
  const float* W_att_in = (const float*)d_in[10];
  const float* b_att_in = (const float*)d_in[11];
  const float* W_att_h = (const float*)d_in[12];
  const float* b_att_h = (const float*)d_in[13];
  const float* V = (const float*)d_in[14];

  float* ws = (float*)d_ws;
  float* ctxp = ws;                     // 524288
  float* Yf = ctxp + 524288;            // 9*131200
  float* qF = Yf + 1180800;             // 65536
  float* qH = qF + 65536;               // 65536
  float* qb = qH + 65536;               // 128
  float* brow2 = qb + 128;              // 1024 each
  float* brow4 = brow2 + 1024;
  float* brow8 = brow4 + 1024;
  float* brow16 = brow8 + 1024;
  float* brow32 = brow16 + 1024;
  int* rowmap = (int*)(brow32 + 1024);  // 512
  __hip_bfloat16* bfp = (__hip_bfloat16*)(rowmap + 512);
  __hip_bfloat16* Mb0 = bfp;             // 1025*1024
  __hip_bfloat16* Mb0T = Mb0 + 1049600;  // 1024*1024
  __hip_bfloat16* Mb1 = Mb0T + 1048576;
  __hip_bfloat16* Mb1T = Mb1 + 1049600;
  __hip_bfloat16* Mb2 = Mb1T + 1048576;
  __hip_bfloat16* Mb2T = Mb2 + 1049600;
  __hip_bfloat16* Mb3 = Mb2T + 1048576;
  __hip_bfloat16* Mb3T = Mb3 + 1049600;
  __hip_bfloat16* YT = Mb3T + 1048576;   // 9 * 131072
  __hip_bfloat16* WahT = YT + 9 * 131072;
  __hip_bfloat16* WaiT = WahT + 131072;  // WaTop^T [128][1024]
  __hip_bfloat16* WcT = WaiT + 131072;   // [128][768]
  __hip_bfloat16* Winb = WcT + 98304;    // [768][1024]
  __hip_bfloat16* Gb = Winb + 786432;    // [64][1024]
  float* out = (float*)d_out;

  auto Yfr = [&](int r) { return Yf + (long)r * 131200; };
  auto YTs = [&](int r) { return YT + (long)r * 131072; };
  const long MB = 1024L * 1024;

  kcast<<<dim3(804), dim3(256), 0, stream>>>(W_s, b_s, context, b_in, W_att_in,
                                             b_att_in, W_att_h, W_in, ids, Mb0,
                                             Mb0T, YTs(0), WahT, WaiT, Winb, Gb,
                                             qb, rowmap);
  // L1: M2, M2T, Z1, Z1T, ctx_proj, WcT
  {
    GBatch bt{}; int c = 0;
    bt.d[0] = mk(Mb0, 0, 1024, nullptr, Mb0T, 1024, 1025, 1024, 1024, b_s, nullptr, nullptr, Mb1, brow2, c); c += bt.d[0].nblks;
    bt.d[1] = mk(Mb0T, 0, 1024, nullptr, Mb0, 1024, 1024, 1024, 1024, nullptr, nullptr, nullptr, Mb1T, nullptr, c); c += bt.d[1].nblks;
    bt.d[2] = mk(Mb0, 0, 1024, nullptr, YTs(0), 1024, 1025, 128, 1024, nullptr, nullptr, Yfr(1), nullptr, nullptr, c); c += bt.d[2].nblks;
    bt.d[3] = mk(YTs(0), 0, 1024, nullptr, Mb0, 1024, 128, 1024, 1024, nullptr, nullptr, nullptr, YTs(1), nullptr, c); c += bt.d[3].nblks;
    bt.d[4] = mk(context, 1, 1024, nullptr, WahT, 1024, 4096, 128, 1024, nullptr, b_att_h, ctxp, nullptr, nullptr, c); c += bt.d[4].nblks;
    bt.d[5] = mk(WaiT, 0, 1024, nullptr, Winb, 1024, 128, 768, 1024, nullptr, nullptr, nullptr, WcT, nullptr, c); c += bt.d[5].nblks;
    bt.nd = 6;
    gemmz<<<dim3(c), dim3(256), 0, stream>>>(bt);
  }
  // L2: M4, M4T, Z2, Z2T, Z3, Z3T
  {
    GBatch bt{}; int c = 0;
    bt.d[0] = mk(Mb1, 0, 1024, nullptr, Mb1T, 1024, 1025, 1024, 1024, brow2, nullptr, nullptr, Mb2, brow4, c); c += bt.d[0].nblks;
    bt.d[1] = mk(Mb1T, 0, 1024, nullptr, Mb1, 1024, 1024, 1024, 1024, nullptr, nullptr, nullptr, Mb2T, nullptr, c); c += bt.d[1].nblks;
    bt.d[2] = mk(Mb1, 0, 1024, nullptr, YTs(0), 1024, 1025, 128, 1024, nullptr, nullptr, Yfr(2), nullptr, nullptr, c); c += bt.d[2].nblks;
    bt.d[3] = mk(YTs(0), 0, 1024, nullptr, Mb1, 1024, 128, 1024, 1024, nullptr, nullptr, nullptr, YTs(2), nullptr, c); c += bt.d[3].nblks;
    bt.d[4] = mk(Mb1, 0, 1024, nullptr, YTs(1), 1024, 1025, 128, 1024, Yfr(1) + 131072, nullptr, Yfr(3), nullptr, nullptr, c); c += bt.d[4].nblks;
    bt.d[5] = mk(YTs(1), 0, 1024, nullptr, Mb1, 1024, 128, 1024, 1024, nullptr, nullptr, nullptr, YTs(3), nullptr, c); c += bt.d[5].nblks;
    bt.nd = 6;
    gemmz<<<dim3(c), dim3(256), 0, stream>>>(bt);
  }
  // L3: M8, M8T, Z4..Z7 (+T)
  {
    GBatch bt{}; int c = 0;
    bt.d[0] = mk(Mb2, 0, 1024, nullptr, Mb2T, 1024, 1025, 1024, 1024, brow4, nullptr, nullptr, Mb3, brow8, c); c += bt.d[0].nblks;
    bt.d[1] = mk(Mb2T, 0, 1024, nullptr, Mb2, 1024, 1024, 1024, 1024, nullptr, nullptr, nullptr, Mb3T, nullptr, c); c += bt.d[1].nblks;
    int k = 2;
    for (int s = 0; s < 4; ++s) {
      bt.d[k] = mk(Mb2, 0, 1024, nullptr, YTs(s), 1024, 1025, 128, 1024,
                   (s == 0) ? nullptr : (Yfr(s) + 131072), nullptr, Yfr(4 + s),
                   nullptr, nullptr, c);
      c += bt.d[k].nblks; ++k;
      bt.d[k] = mk(YTs(s), 0, 1024, nullptr, Mb2, 1024, 128, 1024, 1024, nullptr,
                   nullptr, nullptr, YTs(4 + s), nullptr, c);
      c += bt.d[k].nblks; ++k;
    }
    bt.nd = 10;
    gemmz<<<dim3(c), dim3(256), 0, stream>>>(bt);
  }
  // L4: M16, M16T, Z8, Z8T, g1 = g0*P8 + b8
  {
    GBatch bt{}; int c = 0;
    bt.d[0] = mk(Mb3, 0, 1024, nullptr, Mb3T, 1024, 1025, 1024, 1024, brow8, nullptr, nullptr, Mb1, brow16, c); c += bt.d[0].nblks;
    bt.d[1] = mk(Mb3T, 0, 1024, nullptr, Mb3, 1024, 1024, 1024, 1024, nullptr, nullptr, nullptr, Mb1T, nullptr, c); c += bt.d[1].nblks;
    bt.d[2] = mk(Mb3, 0, 1024, nullptr, YTs(0), 1024, 1025, 128, 1024, nullptr, nullptr, Yfr(8), nullptr, nullptr, c); c += bt.d[2].nblks;
    bt.d[3] = mk(YTs(0), 0, 1024, nullptr, Mb3, 1024, 128, 1024, 1024, nullptr, nullptr, nullptr, YTs(8), nullptr, c); c += bt.d[3].nblks;
    bt.d[4] = mk(Gb, 0, 1024, nullptr, Mb3T, 1024, 8, 1024, 1024, nullptr, brow8, nullptr, Gb + 8192, nullptr, c); c += bt.d[4].nblks;
    bt.nd = 5;
    gemmz<<<dim3(c), dim3(256), 0, stream>>>(bt);
  }
  // L5: M32T = M16T*M16T^T ; brow32 = b16*P16 + b16 ; [g2,g3] = [g0,g1]*P16 + b16
  {
    GBatch bt{}; int c = 0;
    bt.d[0] = mk(Mb1T, 0, 1024, nullptr, Mb1, 1024, 1024, 1024, 1024, nullptr, nullptr, nullptr, Mb2T, nullptr, c); c += bt.d[0].nblks;
    bt.d[1] = mk(Mb1 + MB, 0, 1024, nullptr, Mb1T, 1024, 1, 1024, 1024, nullptr, brow16, brow32, nullptr, nullptr, c); c += bt.d[1].nblks;
    bt.d[2] = mk(Gb, 0, 1024, nullptr, Mb1T, 1024, 16, 1024, 1024, nullptr, brow16, nullptr, Gb + 16384, nullptr, c); c += bt.d[2].nblks;
    bt.nd = 3;
    gemmz<<<dim3(c), dim3(256), 0, stream>>>(bt);
  }
  // L6: [g4..g7] = [g0..g3]*P32 + b32
  {
    GBatch bt{}; int c = 0;
    bt.d[0] = mk(Gb, 0, 1024, nullptr, Mb2T, 1024, 32, 1024, 1024, nullptr, brow32, nullptr, Gb + 32768, nullptr, c); c += bt.d[0].nblks;
    bt.nd = 1;
    gemmz<<<dim3(c), dim3(256), 0, stream>>>(bt);
  }
  // L7: qH_r = G*Z_r + c_r (r=1..8) ; qF = emb[rowmap]*Wc + qb
  {
    GBatch bt{}; int c = 0;
    for (int r = 1; r <= 8; ++r) {
      bt.d[r - 1] = mk(Gb, 0, 1024, nullptr, YTs(r), 1024, 64, 128, 1024, nullptr,
                       Yfr(r) + 131072, qH + (long)(r - 1) * 8192, nullptr, nullptr, c);
      c += bt.d[r - 1].nblks;
    }
    bt.d[8] = mk(emb, 1, 768, rowmap, WcT, 768, 512, 128, 768, nullptr, qb, qF,
                 nullptr, nullptr, c);
    c += bt.d[8].nblks;
    bt.nd = 9;
    gemmz<<<dim3(c), dim3(256), 0, stream>>>(bt);
  }
  katt<<<dim3(256), dim3(256), 0, stream>>>(qF, qH, ctxp, V, out);
}

// Round 8
// 162.111 us; speedup vs baseline: 1.6457x; 1.6457x over previous
//
#include <hip/hip_runtime.h>
#include <hip/hip_bf16.h>

#define EMB 768
#define HD 1024
#define D3 128
#define CTXN 512
#define BB 8
#define SS 64

typedef __attribute__((ext_vector_type(8))) short short8v;
typedef __attribute__((ext_vector_type(4))) float f32x4;

__device__ __forceinline__ float fast_tanh(float x) {
  float e = __expf(2.f * x);
  return 1.f - 2.f * __builtin_amdgcn_rcpf(e + 1.f);
}
__device__ __forceinline__ float bf2f(__hip_bfloat16 x) { return __bfloat162float(x); }

struct GDesc {
  const void* A;                 // row-major [M][K], fp32 or bf16
  const __hip_bfloat16* BT;      // transposed B: [N][K] bf16
  const int* arowmap;            // optional A row gather
  const float* addrow_f;         // added to row M-1 only (affine-aug compose)
  const float* bias_f;           // added to all rows
  float* Cf;                     // fp32 row-major out
  __hip_bfloat16* Cb;            // bf16 row-major out
  __hip_bfloat16* CbT;           // bf16 transposed out [N][ldct], rows<1024 only
  float* brow_f;                 // fp32 copy of row M-1
  int M, N, K, lda, ldbt, ldct, af32, mtiles, blk0, nblks;
};
struct GBatch { GDesc d[10]; int nd; };

// gemmz: 32x64 tile, BK=128, 4 waves (each 16x32), XOR-swizzled LDS, dbuf.
__global__ __launch_bounds__(256) void gemmz(GBatch bat) {
  int bx = blockIdx.x;
  GDesc d = bat.d[0];
  for (int i = 1; i < bat.nd; ++i)
    if (bx >= bat.d[i].blk0) d = bat.d[i];
  int local = bx - d.blk0;
  int mt = local % d.mtiles, nt = local / d.mtiles;
  int bm0 = mt * 32, bn0 = nt * 64;

  __shared__ __hip_bfloat16 As[2][32][128];  // swizzled: 16B-chunk ^ (row&7)
  __shared__ __hip_bfloat16 Bs[2][64][128];
  int tid = threadIdx.x, lane = tid & 63, wid = tid >> 6;
  int l16 = lane & 15, g = lane >> 4;
  int wm = (wid & 1) * 16, wn = (wid >> 1) * 32;
  int arow = tid >> 3, aseg = tid & 7;  // A: 32 rows, 16 el/thread (chunks 2a,2a+1)
  int brow = tid >> 2, bseg = tid & 3;  // B: 64 rows, 32 el/thread (chunks 4b..4b+3)
  f32x4 acc[2] = {};

  int agr = bm0 + arow;
  int asrc = (agr < d.M) ? (d.arowmap ? d.arowmap[agr] : agr) : -1;
  const float* Af = (const float*)d.A;
  const __hip_bfloat16* Ab = (const __hip_bfloat16*)d.A;

  float fa[16];
  short8v ba0 = {}, ba1 = {}, bb0 = {}, bb1 = {}, bb2 = {}, bb3 = {};
  int nk = d.K >> 7;

  auto LD = [&](int k0) {
    if (d.af32) {
      if (asrc >= 0) {
        const float* s = Af + (long)asrc * d.lda + k0 + aseg * 16;
#pragma unroll
        for (int j = 0; j < 16; ++j) fa[j] = s[j];
      } else {
#pragma unroll
        for (int j = 0; j < 16; ++j) fa[j] = 0.f;
      }
    } else {
      if (asrc >= 0) {
        const __hip_bfloat16* s = Ab + (long)asrc * d.lda + k0 + aseg * 16;
        ba0 = *(const short8v*)s;
        ba1 = *(const short8v*)(s + 8);
      } else {
        short8v z = {};
        ba0 = z; ba1 = z;
      }
    }
    const __hip_bfloat16* bsrc = d.BT + (long)(bn0 + brow) * d.ldbt + k0 + bseg * 32;
    bb0 = *(const short8v*)bsrc;
    bb1 = *(const short8v*)(bsrc + 8);
    bb2 = *(const short8v*)(bsrc + 16);
    bb3 = *(const short8v*)(bsrc + 24);
  };
  auto ST = [&](int buf) {
    int rs = arow & 7;
    if (d.af32) {
      __hip_bfloat16 t8[16];
#pragma unroll
      for (int j = 0; j < 16; ++j) t8[j] = __float2bfloat16(fa[j]);
      *(short8v*)&As[buf][arow][((2 * aseg) ^ rs) * 8] = *(short8v*)t8;
      *(short8v*)&As[buf][arow][((2 * aseg + 1) ^ rs) * 8] = *(short8v*)(t8 + 8);
    } else {
      *(short8v*)&As[buf][arow][((2 * aseg) ^ rs) * 8] = ba0;
      *(short8v*)&As[buf][arow][((2 * aseg + 1) ^ rs) * 8] = ba1;
    }
    int rb = brow & 7;
    *(short8v*)&Bs[buf][brow][((4 * bseg) ^ rb) * 8] = bb0;
    *(short8v*)&Bs[buf][brow][((4 * bseg + 1) ^ rb) * 8] = bb1;
    *(short8v*)&Bs[buf][brow][((4 * bseg + 2) ^ rb) * 8] = bb2;
    *(short8v*)&Bs[buf][brow][((4 * bseg + 3) ^ rb) * 8] = bb3;
  };

  LD(0);
  ST(0);
  __syncthreads();
  for (int it = 0; it < nk; ++it) {
    int cur = it & 1;
    if (it + 1 < nk) LD((it + 1) << 7);
    int ar = wm + l16;
    int ars = ar & 7;
#pragma unroll
    for (int kf = 0; kf < 4; ++kf) {
      short8v a = *(const short8v*)&As[cur][ar][((kf * 4 + g) ^ ars) * 8];
#pragma unroll
      for (int j = 0; j < 2; ++j) {
        int br = wn + j * 16 + l16;
        short8v b = *(const short8v*)&Bs[cur][br][((kf * 4 + g) ^ (br & 7)) * 8];
        acc[j] = __builtin_amdgcn_mfma_f32_16x16x32_bf16(a, b, acc[j], 0, 0, 0);
      }
    }
    if (it + 1 < nk) ST(cur ^ 1);
    __syncthreads();
  }

  // epilogue (final loop sync passed: LDS free)
  float* Cs = (float*)&Bs[0][0][0];  // [64][33] floats = 8448 B
  bool doT = (d.CbT != nullptr);
#pragma unroll
  for (int j = 0; j < 2; ++j)
#pragma unroll
    for (int r = 0; r < 4; ++r) {
      int gl = wm + g * 4 + r, cl = wn + j * 16 + l16;
      int grow = bm0 + gl, gcol = bn0 + cl;
      float v = acc[j][r];
      if (d.bias_f) v += d.bias_f[gcol];
      if (d.addrow_f && grow == d.M - 1) v += d.addrow_f[gcol];
      if (grow < d.M) {
        if (d.Cf) d.Cf[(long)grow * d.N + gcol] = v;
        if (d.Cb) d.Cb[(long)grow * d.N + gcol] = __float2bfloat16(v);
        if (d.brow_f && grow == d.M - 1) d.brow_f[gcol] = v;
      }
      if (doT) Cs[cl * 33 + gl] = v;
    }
  if (doT) {
    __syncthreads();
    int ctrows = d.M < 1024 ? d.M : 1024;
    int n = tid >> 2, ms = (tid & 3) * 8;
    int gm0 = bm0 + ms;
    __hip_bfloat16 t8[8];
#pragma unroll
    for (int jj = 0; jj < 8; ++jj) t8[jj] = __float2bfloat16(Cs[n * 33 + ms + jj]);
    if (gm0 + 7 < ctrows) {
      *(short8v*)&d.CbT[(long)(bn0 + n) * d.ldct + gm0] = *(short8v*)t8;
    } else {
#pragma unroll
      for (int jj = 0; jj < 8; ++jj)
        if (gm0 + jj < ctrows) d.CbT[(long)(bn0 + n) * d.ldct + gm0 + jj] = t8[jj];
    }
  }
}

// kcast: Maug1 bf16, transposes (W_s^T, Wa_bot^T, Wah^T, Wa_top^T), g0, qb, rowmap
__global__ __launch_bounds__(256) void kcast(const float* __restrict__ W_s,
                                             const float* __restrict__ b_s,
                                             const float* __restrict__ context,
                                             const float* __restrict__ b_in,
                                             const float* __restrict__ W_att_in,
                                             const float* __restrict__ b_att_in,
                                             const float* __restrict__ W_att_h,
                                             const int* __restrict__ ids,
                                             __hip_bfloat16* __restrict__ Mb0,
                                             __hip_bfloat16* __restrict__ Mb0T,
                                             __hip_bfloat16* __restrict__ Y0T,
                                             __hip_bfloat16* __restrict__ WahT,
                                             __hip_bfloat16* __restrict__ WaiT,
                                             __hip_bfloat16* __restrict__ Gb,
                                             float* __restrict__ qb,
                                             int* __restrict__ rowmap) {
  int blk = blockIdx.x, tid = threadIdx.x;
  __shared__ __hip_bfloat16 tl[64][65];
  __shared__ float red[2][128];

  auto TP = [&](const float* src, int R, int C, __hip_bfloat16* dst, int tr, int tc) {
    int r0 = tr * 64, c0 = tc * 64;
    {
      int r = tid >> 2, cs = (tid & 3) * 16;
      const float* s = src + (long)(r0 + r) * C + c0 + cs;
#pragma unroll
      for (int j = 0; j < 16; ++j) tl[cs + j][r] = __float2bfloat16(s[j]);
    }
    __syncthreads();
    {
      int c = tid >> 2, rs = (tid & 3) * 16;
      __hip_bfloat16 o[16];
#pragma unroll
      for (int j = 0; j < 16; ++j) o[j] = tl[c][rs + j];
      *(short8v*)&dst[(long)(c0 + c) * R + r0 + rs] = *(short8v*)&o[0];
      *(short8v*)&dst[(long)(c0 + c) * R + r0 + rs + 8] = *(short8v*)&o[8];
    }
  };

  if (blk < 256) {
    long base = (long)blk * 4096;
    for (int i = tid; i < 4096; i += 256)
      Mb0[base + i] = __float2bfloat16(W_s[base + i]);
  } else if (blk == 256) {
    for (int i = tid; i < HD; i += 256)
      Mb0[(long)HD * HD + i] = __float2bfloat16(b_s[i]);
  } else if (blk < 513) {
    int t = blk - 257;
    TP(W_s, 1024, 1024, Mb0T, t >> 4, t & 15);
  } else if (blk < 545) {
    int t = blk - 513;
    TP(W_att_in + (long)1024 * D3, 1024, 128, Y0T, t >> 1, t & 1);
  } else if (blk < 577) {
    int t = blk - 545;
    TP(W_att_h, 1024, 128, WahT, t >> 1, t & 1);
  } else if (blk < 609) {
    int t = blk - 577;
    TP(W_att_in, 1024, 128, WaiT, t >> 1, t & 1);
  } else if (blk == 609) {
    for (int i = tid; i < BB * HD; i += 256) {
      int b = i >> 10, k = i & 1023;
      Gb[i] = __float2bfloat16(context[((long)b * CTXN + CTXN - 1) * HD + k]);
    }
  } else if (blk == 610) {
    int dd = tid & 127, h = tid >> 7;
    float acc = 0.f;
    for (int k = h * 512; k < h * 512 + 512; ++k)
      acc += b_in[k] * W_att_in[k * D3 + dd];
    red[h][dd] = acc;
    __syncthreads();
    if (h == 0) qb[dd] = red[0][dd] + red[1][dd] + b_att_in[dd];
  } else {
    for (int i = tid; i < 512; i += 256) {
      int t = i >> 3, b = i & 7;
      rowmap[i] = ids[b * SS + t];
    }
  }
}

// katt: out[b][t][c] = sum_d V[d]*tanh(qF[t*8+b][d] + qH[t&7][(t>>3)*8+b][d] + ctxp[b][c][d])
__global__ __launch_bounds__(256) void katt(const float* __restrict__ qF,
                                            const float* __restrict__ qH,
                                            const float* __restrict__ ctxp,
                                            const float* __restrict__ V,
                                            float* __restrict__ out) {
  int blk = blockIdx.x;
  int b = blk >> 5, tt = (blk >> 4) & 1, ct = blk & 15;
  int t0 = tt * 32, c0 = ct * 32;
  int tid = threadIdx.x;
  __shared__ float lq[32][128];
  __shared__ float lc[32][132];
  __shared__ float lv[128];
  for (int i = tid; i < 32 * 128; i += 256) {
    int r = i >> 7, d = i & 127;
    int t = t0 + r;
    lq[r][d] = qF[((long)t * 8 + b) * 128 + d] +
               qH[(((long)(t & 7)) * 64 + (t >> 3) * 8 + b) * 128 + d];
    lc[r][d] = ctxp[((long)b * CTXN + c0 + r) * D3 + d];
  }
  if (tid < 128) lv[tid] = V[tid];
  __syncthreads();
  int cl = tid & 31, tg = tid >> 5;
  float r[4] = {0.f, 0.f, 0.f, 0.f};
  for (int d4 = 0; d4 < 32; ++d4) {
    float4 cv = *reinterpret_cast<const float4*>(&lc[cl][d4 * 4]);
    float4 vv = *reinterpret_cast<const float4*>(&lv[d4 * 4]);
#pragma unroll
    for (int u = 0; u < 4; ++u) {
      int t = tg + u * 8;
      float4 qv = *reinterpret_cast<const float4*>(&lq[t][d4 * 4]);
      r[u] = fmaf(vv.x, fast_tanh(qv.x + cv.x), r[u]);
      r[u] = fmaf(vv.y, fast_tanh(qv.y + cv.y), r[u]);
      r[u] = fmaf(vv.z, fast_tanh(qv.z + cv.z), r[u]);
      r[u] = fmaf(vv.w, fast_tanh(qv.w + cv.w), r[u]);
    }
  }
#pragma unroll
  for (int u = 0; u < 4; ++u) {
    int t = tg + u * 8;
    out[((long)b * SS + (t0 + t)) * CTXN + c0 + cl] = r[u];
  }
  if (blk == 0) {
    for (int i = tid; i < SS * BB; i += 256) out[(long)BB * SS * CTXN + i] = 0.f;
  }
}

static inline GDesc mk(const void* A, int af32, int lda, const int* arowmap,
                       const __hip_bfloat16* BT, int ldbt, int M, int N, int K,
                       const float* addrow_f, const float* bias_f, float* Cf,
                       __hip_bfloat16* Cb, __hip_bfloat16* CbT, int ldct,
                       float* brow_f, int blk0) {
  GDesc d;
  d.A = A; d.BT = BT; d.arowmap = arowmap;
  d.addrow_f = addrow_f; d.bias_f = bias_f;
  d.Cf = Cf; d.Cb = Cb; d.CbT = CbT; d.brow_f = brow_f;
  d.M = M; d.N = N; d.K = K; d.lda = lda; d.ldbt = ldbt; d.ldct = ldct;
  d.af32 = af32;
  d.mtiles = (M + 31) >> 5;
  d.blk0 = blk0;
  d.nblks = d.mtiles * (N >> 6);
  return d;
}

extern "C" void kernel_launch(void* const* d_in, const int* in_sizes, int n_in,
                              void* d_out, int out_size, void* d_ws, size_t ws_size,
                              hipStream_t stream) {
  const int* ids = (const int*)d_in[0];
  const float* context = (const float*)d_in[4];
  const float* emb = (const float*)d_in[5];
  const float* W_in = (const float*)d_in[6];
  const float* b_in = (const float*)d_in[7];
  const float* W_s = (const float*)d_in[8];
  const float* b_s = (const float*)d_in[9];
  const float* W_att_in = (const float*)d_in[10];
  const float* b_att_in = (const float*)d_in[11];
  const float* W_att_h = (const float*)d_in[12];
  const float* b_att_h = (const float*)d_in[13];
  const float* V = (const float*)d_in[14];

  float* ws = (float*)d_ws;
  float* ctxp = ws;                     // 524288
  float* Yf = ctxp + 524288;            // 9*131200 (slot r, r=0 unused)
  float* qF = Yf + 1180800;             // 65536
  float* qH = qF + 65536;               // 8*64*128 = 65536
  float* qb = qH + 65536;               // 128
  float* brow2 = qb + 128;              // 1024 each
  float* brow4 = brow2 + 1024;
  float* brow8 = brow4 + 1024;
  float* brow16 = brow8 + 1024;
  int* rowmap = (int*)(brow16 + 1024);  // 512
  __hip_bfloat16* bfp = (__hip_bfloat16*)(rowmap + 512);
  __hip_bfloat16* Mb0 = bfp;            // 1025*1024
  __hip_bfloat16* Mb0T = Mb0 + 1049600; // 1024*1024
  __hip_bfloat16* Mb1 = Mb0T + 1048576;
  __hip_bfloat16* Mb1T = Mb1 + 1049600;
  __hip_bfloat16* Mb2 = Mb1T + 1048576;
  __hip_bfloat16* Mb2T = Mb2 + 1049600;
  __hip_bfloat16* Mb3 = Mb2T + 1048576;
  __hip_bfloat16* Mb3T = Mb3 + 1049600;
  __hip_bfloat16* YT = Mb3T + 1048576;  // 9 slots * 131072
  __hip_bfloat16* WahT = YT + 9 * 131072;
  __hip_bfloat16* WaiT = WahT + 131072;
  __hip_bfloat16* WcT = WaiT + 131072;  // [128][768]
  __hip_bfloat16* Gb = WcT + 131072;    // 64*1024 (rows k*8+b)
  float* out = (float*)d_out;

  auto Yfr = [&](int r) { return Yf + (long)r * 131200; };
  auto YTs = [&](int r) { return YT + (long)r * 131072; };

  kcast<<<dim3(612), dim3(256), 0, stream>>>(W_s, b_s, context, b_in, W_att_in,
                                             b_att_in, W_att_h, ids, Mb0, Mb0T,
                                             YTs(0), WahT, WaiT, Gb, qb, rowmap);
  // L1: M2 = M1^2 ; Z1 = M1*Z0 ; ctx_proj ; WcT
  {
    GBatch bt{}; int c = 0;
    bt.d[0] = mk(Mb0, 0, 1024, nullptr, Mb0T, 1024, 1025, 1024, 1024, b_s, nullptr, nullptr, Mb1, Mb1T, 1024, brow2, c); c += bt.d[0].nblks;
    bt.d[1] = mk(Mb0, 0, 1024, nullptr, YTs(0), 1024, 1025, 128, 1024, nullptr, nullptr, Yfr(1), nullptr, YTs(1), 1024, nullptr, c); c += bt.d[1].nblks;
    bt.d[2] = mk(context, 1, 1024, nullptr, WahT, 1024, 4096, 128, 1024, nullptr, b_att_h, ctxp, nullptr, nullptr, 0, nullptr, c); c += bt.d[2].nblks;
    bt.d[3] = mk(W_in, 1, 1024, nullptr, WaiT, 1024, 768, 128, 1024, nullptr, nullptr, nullptr, nullptr, WcT, 768, nullptr, c); c += bt.d[3].nblks;
    bt.nd = 4;
    gemmz<<<dim3(c), dim3(256), 0, stream>>>(bt);
  }
  // L2: M4 ; Z2 = M2*Z0 ; Z3 = M2∘Z1 ; qF = emb[rowmap]*Wc + qb
  {
    GBatch bt{}; int c = 0;
    bt.d[0] = mk(Mb1, 0, 1024, nullptr, Mb1T, 1024, 1025, 1024, 1024, brow2, nullptr, nullptr, Mb2, Mb2T, 1024, brow4, c); c += bt.d[0].nblks;
    bt.d[1] = mk(Mb1, 0, 1024, nullptr, YTs(0), 1024, 1025, 128, 1024, nullptr, nullptr, Yfr(2), nullptr, YTs(2), 1024, nullptr, c); c += bt.d[1].nblks;
    bt.d[2] = mk(Mb1, 0, 1024, nullptr, YTs(1), 1024, 1025, 128, 1024, Yfr(1) + 131072, nullptr, Yfr(3), nullptr, YTs(3), 1024, nullptr, c); c += bt.d[2].nblks;
    bt.d[3] = mk(emb, 1, 768, rowmap, WcT, 768, 512, 128, 768, nullptr, qb, qF, nullptr, nullptr, 0, nullptr, c); c += bt.d[3].nblks;
    bt.nd = 4;
    gemmz<<<dim3(c), dim3(256), 0, stream>>>(bt);
  }
  // L3: M8 ; Z4..Z7 = M4∘Z0..Z3
  {
    GBatch bt{}; int c = 0;
    bt.d[0] = mk(Mb2, 0, 1024, nullptr, Mb2T, 1024, 1025, 1024, 1024, brow4, nullptr, nullptr, Mb3, Mb3T, 1024, brow8, c); c += bt.d[0].nblks;
    for (int s = 0; s < 4; ++s) {
      bt.d[1 + s] = mk(Mb2, 0, 1024, nullptr, YTs(s), 1024, 1025, 128, 1024,
                       (s == 0) ? nullptr : (Yfr(s) + 131072), nullptr,
                       Yfr(4 + s), nullptr, YTs(4 + s), 1024, nullptr, c);
      c += bt.d[1 + s].nblks;
    }
    bt.nd = 5;
    gemmz<<<dim3(c), dim3(256), 0, stream>>>(bt);
  }
  // L4: M16 ; Z8 = M8*Z0 ; g1 = g0*W8 + b8
  {
    GBatch bt{}; int c = 0;
    bt.d[0] = mk(Mb3, 0, 1024, nullptr, Mb3T, 1024, 1025, 1024, 1024, brow8, nullptr, nullptr, Mb1, Mb1T, 1024, brow16, c); c += bt.d[0].nblks;
    bt.d[1] = mk(Mb3, 0, 1024, nullptr, YTs(0), 1024, 1025, 128, 1024, nullptr, nullptr, Yfr(8), nullptr, YTs(8), 1024, nullptr, c); c += bt.d[1].nblks;
    bt.d[2] = mk(Gb, 0, 1024, nullptr, Mb3T, 1024, 8, 1024, 1024, nullptr, brow8, nullptr, Gb + 8192, nullptr, 0, nullptr, c); c += bt.d[2].nblks;
    bt.nd = 3;
    gemmz<<<dim3(c), dim3(256), 0, stream>>>(bt);
  }
  // L5: [g2,g3] = [g0,g1]*W16 + b16 ; qH(k=0,1; r=1..8)
  // L6: [g4,g5] = [g2,g3]*W16 + b16 ; qH(k=2,3)
  // L7: [g6,g7] = [g4,g5]*W16 + b16 ; qH(k=4,5)
  for (int lev = 0; lev < 3; ++lev) {
    GBatch bt{}; int c = 0;
    bt.d[0] = mk(Gb + (long)lev * 16384, 0, 1024, nullptr, Mb1T, 1024, 16, 1024, 1024,
                 nullptr, brow16, nullptr, Gb + (long)(lev + 1) * 16384, nullptr, 0,
                 nullptr, c);
    c += bt.d[0].nblks;
    for (int r = 1; r <= 8; ++r) {
      bt.d[r] = mk(Gb + (long)lev * 16384, 0, 1024, nullptr, YTs(r), 1024, 16, 128,
                   1024, nullptr, Yfr(r) + 131072,
                   qH + (long)(r - 1) * 8192 + (long)lev * 2048, nullptr, nullptr, 0,
                   nullptr, c);
      c += bt.d[r].nblks;
    }
    bt.nd = 9;
    gemmz<<<dim3(c), dim3(256), 0, stream>>>(bt);
  }
  // L8: qH(k=6,7)
  {
    GBatch bt{}; int c = 0;
    for (int r = 1; r <= 8; ++r) {
      bt.d[r - 1] = mk(Gb + 49152, 0, 1024, nullptr, YTs(r), 1024, 16, 128, 1024,
                       nullptr, Yfr(r) + 131072,
                       qH + (long)(r - 1) * 8192 + 6144, nullptr, nullptr, 0,
                       nullptr, c);
      c += bt.d[r - 1].nblks;
    }
    bt.nd = 8;
    gemmz<<<dim3(c), dim3(256), 0, stream>>>(bt);
  }
  katt<<<dim3(256), dim3(256), 0, stream>>>(qF, qH, ctxp, V, out);
}